// Round 3
// baseline (837.567 us; speedup 1.0000x reference)
//
#include <hip/hip_runtime.h>
#include <hip/hip_bf16.h>

#define E_EDGES 800000
#define N_NODES_ 50000
#define EPS_ 1e-5f
#define N_SCAN_BLOCKS 49   // ceil(50000/1024)

#define M_GRID   1250      // 6250 tiles / 1250 blocks = 5 tiles each, exact
#define M_ITERS  5
#define M_SPLITS 25        // reduce: 1250 blocks / 25 = 50 blocks per split

#define AGG_EPW  16        // edges per wave in agg (sorted perm slots)

typedef float f32x4 __attribute__((ext_vector_type(4)));
typedef short s16x8 __attribute__((ext_vector_type(8)));

// ---- workspace layout (4-byte word offsets) ----
#define OFF_M      0                          // [88*88] fp32 (reduced into)
#define OFF_CS     (88 * 88)                  // [88] fp32 col sums
#define OFF_CNT    (OFF_CS + 88)              // [N] int histogram (atomics)
#define OFF_AGG    (OFF_CNT + N_NODES_)       // [N*88] fp32 (atomic agg -> zeroed)
#define ZERO_WORDS (OFF_AGG + N_NODES_ * 88)  // zero M + cs + cnt + agg (~17.8MB)
#define OFF_CUR    ZERO_WORDS                 // [N] int scan/cursor
#define OFF_PART   (OFF_CUR + N_NODES_)       // [64] int scan partials
#define OFF_PERM   (OFF_PART + 64)            // [E] int edge permutation
#define OFF_V      (OFF_PERM + E_EDGES)       // [88*128] fp32 M@W1
#define OFF_S      (OFF_V + 88 * 128)         // [128]
#define OFF_T      (OFF_S + 128)              // [128]
#define OFF_MPART  (OFF_T + 128)              // [1250 * 5376] fp32 per-block M partials

// ---------------------------------------------------------------------------
// M = G^T G via MFMA. Coalesced staging (contiguous 43KB tile range, float2
// per lane) + register software pipeline: tile t+1 loads in flight during
// tile t's LDS-write + MFMA. Transposed LDS Gs_t[feat][edge], stride 136
// shorts (272B, 16B-aligned rows for ds_read_b128 fragments).
// Upper-triangular 16x16 tiles only (21), hardcoded per wave.
// Flush: per-block partial stores (coalesced), reduced by m_reduce_kernel
// (R1->R2: removed 8.3M same-address atomics, -162us).
// R3: occupancy 3->6 blocks/CU + grid 625->1250 for latency hiding of the
// streaming loads (R1 Occupancy was 25%).
// ---------------------------------------------------------------------------
__global__ __launch_bounds__(256, 6)
void m_kernel(const float* __restrict__ x, const int* __restrict__ eidx,
              const float* __restrict__ ea, float* __restrict__ mpart)
{
    __shared__ __align__(16) short Gs_t[96 * 136];

    const int tid  = threadIdx.x;
    const int lane = tid & 63;
    const int wave = tid >> 6;         // 0..3
    const int m    = lane & 15;
    const int q    = lane >> 4;        // 0..3

    f32x4 acc[6];
#pragma unroll
    for (int i = 0; i < 6; ++i) acc[i] = (f32x4){0.f, 0.f, 0.f, 0.f};

    // zero pad rows 88..95 once (staging never writes them)
    {
        int* gz = (int*)&Gs_t[88 * 136];
        for (int i = tid; i < 8 * 136 / 2; i += 256) gz[i] = 0;
    }

    // precompute LDS short-index for each of this thread's 21 float2 slots
    unsigned addrL[21];
#pragma unroll
    for (int i = 0; i < 21; ++i) {
        const int d = (i * 256 + tid) * 2;   // dword index in tile, even
        const int e = d / 84;
        const int f = d - e * 84;            // even, <= 82
        addrL[i] = (unsigned)((4 + f) * 136 + e);
    }

    int tile = blockIdx.x;
    // ---- prologue: tile0 in flight ----
    int colA = 0, colB = 0;
    if (tid < 128) colA = eidx[E_EDGES + tile * 128 + tid];
    float2 r[21];
    {
        const float2* tb = (const float2*)ea + (size_t)tile * 5376;
#pragma unroll
        for (int i = 0; i < 21; ++i) r[i] = tb[i * 256 + tid];
    }
    float4 xv = (float4){0.f, 0.f, 0.f, 0.f};
    if (tid < 128) xv = *(const float4*)(x + (size_t)colA * 4);
    if (tid < 128) colB = eidx[E_EDGES + (tile + M_GRID) * 128 + tid];

#pragma unroll 1
    for (int it = 0; it < M_ITERS; ++it) {
        __syncthreads();               // previous tile's MFMA reads done

        // stage x rows 0..3
        if (tid < 128) {
            __hip_bfloat16 b0 = __float2bfloat16(xv.x);
            __hip_bfloat16 b1 = __float2bfloat16(xv.y);
            __hip_bfloat16 b2 = __float2bfloat16(xv.z);
            __hip_bfloat16 b3 = __float2bfloat16(xv.w);
            Gs_t[0 * 136 + tid] = *(short*)&b0;
            Gs_t[1 * 136 + tid] = *(short*)&b1;
            Gs_t[2 * 136 + tid] = *(short*)&b2;
            Gs_t[3 * 136 + tid] = *(short*)&b3;
        }
        // stage ea rows 4..87 (transpose)
#pragma unroll
        for (int i = 0; i < 21; ++i) {
            __hip_bfloat16 b0 = __float2bfloat16(r[i].x);
            __hip_bfloat16 b1 = __float2bfloat16(r[i].y);
            Gs_t[addrL[i]]       = *(short*)&b0;
            Gs_t[addrL[i] + 136] = *(short*)&b1;
        }

        // prefetch next tile (stays in flight through MFMA phase)
        const int next = tile + M_GRID;
        if (it + 1 < M_ITERS) {
            const float2* tbn = (const float2*)ea + (size_t)next * 5376;
#pragma unroll
            for (int i = 0; i < 21; ++i) r[i] = tbn[i * 256 + tid];
            if (tid < 128) xv = *(const float4*)(x + (size_t)colB * 4);
            if (tid < 128 && it + 2 < M_ITERS)
                colB = eidx[E_EDGES + (next + M_GRID) * 128 + tid];
        }
        __syncthreads();

#pragma unroll
        for (int kk = 0; kk < 4; ++kk) {
            const int kbase = kk * 32 + q * 8;
            s16x8 fr[6];
#pragma unroll
            for (int p = 0; p < 6; ++p)
                fr[p] = *reinterpret_cast<const s16x8*>(
                            &Gs_t[(p * 16 + m) * 136 + kbase]);
#define MM(i, a, b) acc[i] = __builtin_amdgcn_mfma_f32_16x16x32_bf16(fr[a], fr[b], acc[i], 0, 0, 0)
            if      (wave == 0) { MM(0,0,0); MM(1,0,4); MM(2,1,3); MM(3,2,3); MM(4,3,4); MM(5,5,5); }
            else if (wave == 1) { MM(0,0,1); MM(1,0,5); MM(2,1,4); MM(3,2,4); MM(4,3,5); }
            else if (wave == 2) { MM(0,0,2); MM(1,1,1); MM(2,1,5); MM(3,2,5); MM(4,4,4); }
            else                { MM(0,0,3); MM(1,1,2); MM(2,2,2); MM(3,3,3); MM(4,4,5); }
#undef MM
        }
        tile = next;
    }

    // flush: coalesced partial stores. pos = k*256 + m*16 + (q*4+r0);
    // a wave's f32x4 store covers floats 0..255 of tile k contiguously.
    {
        float* pb = mpart + (size_t)blockIdx.x * 5376;
        const int nt = (wave == 0) ? 6 : 5;
#pragma unroll
        for (int i = 0; i < 6; ++i) {
            if (i < nt) {
                const int k = wave + i * 4;
                *(f32x4*)(pb + k * 256 + m * 16 + q * 4) = acc[i];
            }
        }
    }
}

// reduce per-block M partials into M. grid = 5376*M_SPLITS/256 blocks.
// Each (pos, split) sums 50 blocks' partials then atomicAdd (134K atomics,
// well spread).
__global__ __launch_bounds__(256)
void m_reduce_kernel(const float* __restrict__ mpart, float* __restrict__ M)
{
    const int g     = blockIdx.x * 256 + threadIdx.x;
    const int pos   = g % 5376;
    const int split = g / 5376;
    const int b0    = split * (M_GRID / M_SPLITS);
    const int b1    = b0 + (M_GRID / M_SPLITS);

    float s = 0.f;
#pragma unroll 5
    for (int b = b0; b < b1; ++b) s += mpart[(size_t)b * 5376 + pos];

    const int k  = pos >> 8;
    const int wi = pos & 255;
    const int m  = wi >> 4;
    const int qr = wi & 15;
    const int tr = (k >= 20) ? 5 : (k >= 18) ? 4 : (k >= 15) ? 3
                 : (k >= 11) ? 2 : (k >= 6) ? 1 : 0;
    const int S  = (tr == 5) ? 20 : (tr == 4) ? 18 : (tr == 3) ? 15
                 : (tr == 2) ? 11 : (tr == 1) ? 6 : 0;
    const int tc = tr + (k - S);
    const int rr = tr * 16 + qr;
    const int c  = tc * 16 + m;
    if (rr < 88 && c < 88) {
        atomicAdd(&M[rr * 88 + c], s);
        if (tr != tc) atomicAdd(&M[c * 88 + rr], s);
    }
}

// ---- counting sort: histogram -> scan -> scatter ----
__global__ void hist_kernel(const int* __restrict__ eidx, int* __restrict__ cnt)
{
    int e = blockIdx.x * 256 + threadIdx.x;
    if (e < E_EDGES) atomicAdd(&cnt[eidx[e]], 1);
}

__global__ void scan1_kernel(const int* __restrict__ cnt, int* __restrict__ partial)
{
    __shared__ int l[1024];
    int i = blockIdx.x * 1024 + threadIdx.x;
    l[threadIdx.x] = (i < N_NODES_) ? cnt[i] : 0;
    __syncthreads();
    for (int s = 512; s > 0; s >>= 1) {
        if (threadIdx.x < s) l[threadIdx.x] += l[threadIdx.x + s];
        __syncthreads();
    }
    if (threadIdx.x == 0) partial[blockIdx.x] = l[0];
}

__global__ void scan2_kernel(int* __restrict__ partial)
{
    if (threadIdx.x == 0) {
        int acc = 0;
        for (int i = 0; i < N_SCAN_BLOCKS; ++i) {
            int t = partial[i]; partial[i] = acc; acc += t;
        }
    }
}

__global__ void scan3_kernel(const int* __restrict__ cnt, const int* __restrict__ partial,
                             int* __restrict__ cursor)
{
    __shared__ int l[1024];
    int i = blockIdx.x * 1024 + threadIdx.x;
    int v = (i < N_NODES_) ? cnt[i] : 0;
    l[threadIdx.x] = v;
    __syncthreads();
    for (int s = 1; s < 1024; s <<= 1) {
        int t = (threadIdx.x >= s) ? l[threadIdx.x - s] : 0;
        __syncthreads();
        l[threadIdx.x] += t;
        __syncthreads();
    }
    if (i < N_NODES_) cursor[i] = partial[blockIdx.x] + l[threadIdx.x] - v; // exclusive
}

__global__ void scatter_kernel(const int* __restrict__ eidx, int* __restrict__ cursor,
                               int* __restrict__ perm)
{
    int e = blockIdx.x * 256 + threadIdx.x;
    if (e < E_EDGES) {
        int pos = atomicAdd(&cursor[eidx[e]], 1);
        perm[pos] = e;
    }
}

// ---------------------------------------------------------------------------
// Edge-parallel aggregation over SORTED perm: one wave per 16 perm slots.
// No inter-iteration dependence (all edge ids staged first, then 32
// independent ea loads per wave can be in flight). Runs of equal row
// accumulate in registers; segment boundaries flush via spread atomicAdd
// (~8.8M atomics over 4.4M addresses, ~2-way contention). Replaces the
// node-parallel version whose per-wave serial chain (deg/2 dependent
// iterations) was latency-bound.
// ---------------------------------------------------------------------------
__global__ __launch_bounds__(256)
void agg_kernel(const float* __restrict__ x, const int* __restrict__ eidx,
                const float* __restrict__ ea, const int* __restrict__ perm,
                float* __restrict__ agg)
{
    __shared__ int eL[4][AGG_EPW];
    __shared__ int rL[4][AGG_EPW];
    __shared__ int cL[4][AGG_EPW];

    const int tid  = threadIdx.x;
    const int lane = tid & 63;
    const int wv   = tid >> 6;
    const int base = (blockIdx.x * 4 + wv) * AGG_EPW;   // 12500*4*16 = 800000 exact

    if (lane < AGG_EPW) {
        int e = perm[base + lane];
        eL[wv][lane] = e;
        rL[wv][lane] = eidx[e];
        cL[wv][lane] = eidx[E_EDGES + e];
    }
    __syncthreads();

    float a0 = 0.f, a1 = 0.f;
    int cur = rL[wv][0];
#pragma unroll
    for (int j = 0; j < AGG_EPW; ++j) {
        const int e   = eL[wv][j];
        const int row = rL[wv][j];
        const int col = cL[wv][j];
        const float* p = ea + (size_t)e * 84;
        float v0 = (lane < 4) ? x[(size_t)col * 4 + lane] : p[lane - 4];
        float v1 = (lane < 24) ? p[60 + lane] : 0.f;
        if (row != cur) {              // wave-uniform (row broadcast from LDS)
            atomicAdd(&agg[(size_t)cur * 88 + lane], a0);
            if (lane < 24) atomicAdd(&agg[(size_t)cur * 88 + 64 + lane], a1);
            a0 = 0.f; a1 = 0.f; cur = row;
        }
        a0 += v0;
        a1 += v1;
    }
    atomicAdd(&agg[(size_t)cur * 88 + lane], a0);
    if (lane < 24) atomicAdd(&agg[(size_t)cur * 88 + 64 + lane], a1);
}

// cs[f] = sum over nodes of agg[n][f]
__global__ void colsum_kernel(const float* __restrict__ agg, float* __restrict__ cs)
{
    const int f = threadIdx.x;
    if (f >= 88) return;
    float a = 0.f;
    for (int n = blockIdx.x; n < N_NODES_; n += gridDim.x) a += agg[n * 88 + f];
    atomicAdd(&cs[f], a);
}

// v = M @ W1   [88 x 128]
__global__ void mv_kernel(const float* __restrict__ M, const float* __restrict__ W1,
                          float* __restrict__ v)
{
    const int a = blockIdx.x;
    const int j = threadIdx.x;
    float acc = 0.f;
    for (int b = 0; b < 88; ++b) acc += M[a * 88 + b] * W1[b * 128 + j];
    v[a * 128 + j] = acc;
}

__global__ void stats_kernel(const float* __restrict__ cs, const float* __restrict__ v,
                             const float* __restrict__ W1, const float* __restrict__ b1,
                             const float* __restrict__ gamma, const float* __restrict__ beta,
                             float* __restrict__ s, float* __restrict__ t)
{
    const int j = threadIdx.x;
    const float invE = 1.0f / (float)E_EDGES;
    float mu = 0.f, eh2 = 0.f;
    for (int a = 0; a < 88; ++a) {
        float w = W1[a * 128 + j];
        mu  += cs[a] * w;
        eh2 += v[a * 128 + j] * w;
    }
    mu *= invE;
    eh2 *= invE;
    float var  = eh2 - mu * mu;
    float mean = mu + b1[j];
    float inv  = rsqrtf(var + EPS_);
    float sj   = gamma[j] * inv;
    s[j] = sj;
    t[j] = beta[j] - mean * sj;
}

__global__ __launch_bounds__(128)
void node_kernel(const float* __restrict__ x, const float* __restrict__ agg,
                 const int* __restrict__ cnt, const float* __restrict__ W1,
                 const float* __restrict__ b1, const float* __restrict__ W2,
                 const float* __restrict__ b2, const float* __restrict__ s,
                 const float* __restrict__ t, float* __restrict__ out)
{
    __shared__ float aggL[4 * 88];
    __shared__ float featL[4][128];
    __shared__ float cntL[4];
    __shared__ float xL[16];
    const int tid = threadIdx.x;
    const int nbase = blockIdx.x * 4;

    for (int i = tid; i < 352; i += 128) aggL[i] = agg[nbase * 88 + i];
    if (tid < 4)  cntL[tid] = (float)cnt[nbase + tid];
    if (tid < 16) xL[tid] = x[nbase * 4 + tid];
    __syncthreads();

    {
        const int j = tid;
        float a0 = 0.f, a1 = 0.f, a2 = 0.f, a3 = 0.f;
        for (int a = 0; a < 88; ++a) {
            float w = W1[a * 128 + j];
            a0 += aggL[a]       * w;
            a1 += aggL[88 + a]  * w;
            a2 += aggL[176 + a] * w;
            a3 += aggL[264 + a] * w;
        }
        const float sj = s[j], tj = t[j], bj = b1[j];
        float accs[4] = {a0, a1, a2, a3};
#pragma unroll
        for (int n = 0; n < 4; ++n) {
            float c = cntL[n];
            featL[n][j] = (c > 0.f) ? (sj * (accs[n] / c + bj) + tj) : 0.f;
        }
    }
    __syncthreads();

    {
        const int jc = tid & 63;
        const int nh = tid >> 6;
#pragma unroll
        for (int h = 0; h < 2; ++h) {
            const int n = nh * 2 + h;
            float acc = b2[jc];
#pragma unroll
            for (int k = 0; k < 4; ++k) acc += xL[n * 4 + k] * W2[k * 64 + jc];
            for (int k = 0; k < 128; ++k)
                acc += featL[n][k] * W2[(4 + k) * 64 + jc];
            out[(nbase + n) * 64 + jc] = fmaxf(acc, 0.f);
        }
    }
}

extern "C" void kernel_launch(void* const* d_in, const int* in_sizes, int n_in,
                              void* d_out, int out_size, void* d_ws, size_t ws_size,
                              hipStream_t stream)
{
    const float* x     = (const float*)d_in[0];
    const int*   eidx  = (const int*)d_in[1];
    const float* ea    = (const float*)d_in[2];
    const float* W1    = (const float*)d_in[3];
    const float* b1    = (const float*)d_in[4];
    const float* gamma = (const float*)d_in[5];
    const float* beta  = (const float*)d_in[6];
    const float* W2    = (const float*)d_in[7];
    const float* b2    = (const float*)d_in[8];

    float* ws    = (float*)d_ws;
    float* M     = ws + OFF_M;
    float* cs    = ws + OFF_CS;
    int*   cnt   = (int*)(ws + OFF_CNT);
    float* agg   = ws + OFF_AGG;
    int*   cur   = (int*)(ws + OFF_CUR);
    int*   part  = (int*)(ws + OFF_PART);
    int*   perm  = (int*)(ws + OFF_PERM);
    float* v     = ws + OFF_V;
    float* s     = ws + OFF_S;
    float* t     = ws + OFF_T;
    float* mpart = ws + OFF_MPART;
    float* out   = (float*)d_out;

    hipMemsetAsync(d_ws, 0, (size_t)ZERO_WORDS * sizeof(float), stream);

    hist_kernel<<<(E_EDGES + 255) / 256, 256, 0, stream>>>(eidx, cnt);
    scan1_kernel<<<N_SCAN_BLOCKS, 1024, 0, stream>>>(cnt, part);
    scan2_kernel<<<1, 64, 0, stream>>>(part);
    scan3_kernel<<<N_SCAN_BLOCKS, 1024, 0, stream>>>(cnt, part, cur);
    scatter_kernel<<<(E_EDGES + 255) / 256, 256, 0, stream>>>(eidx, cur, perm);

    m_kernel<<<M_GRID, 256, 0, stream>>>(x, eidx, ea, mpart);
    m_reduce_kernel<<<(5376 * M_SPLITS) / 256, 256, 0, stream>>>(mpart, M);
    agg_kernel<<<E_EDGES / (4 * AGG_EPW), 256, 0, stream>>>(x, eidx, ea, perm, agg);

    colsum_kernel<<<512, 96, 0, stream>>>(agg, cs);
    mv_kernel<<<88, 128, 0, stream>>>(M, W1, v);
    stats_kernel<<<1, 128, 0, stream>>>(cs, v, W1, b1, gamma, beta, s, t);
    node_kernel<<<12500, 128, 0, stream>>>(x, agg, cnt, W1, b1, W2, b2, s, t, out);
}

// Round 4
// 784.408 us; speedup vs baseline: 1.0678x; 1.0678x over previous
//
#include <hip/hip_runtime.h>
#include <hip/hip_bf16.h>

#define E_EDGES 800000
#define N_NODES_ 50000
#define EPS_ 1e-5f
#define N_SCAN_BLOCKS 49   // ceil(50000/1024)

#define M_GRID   625       // blocks in fused kernel
#define M_TILES  10        // 6250 tiles / 625 blocks, exact
#define M_SPLITS 25        // reduce: 625 blocks / 25 = 25 blocks per split

typedef float f32x4 __attribute__((ext_vector_type(4)));
typedef short s16x8 __attribute__((ext_vector_type(8)));

// ---- workspace layout (4-byte word offsets) ----
#define OFF_M      0                          // [88*88] fp32 (reduced into)
#define OFF_CS     (88 * 88)                  // [88] fp32 col sums
#define OFF_CNT    (OFF_CS + 88)              // [N] int histogram (atomics)
#define OFF_AGG    (OFF_CNT + N_NODES_)       // [N*88] fp32 (atomic agg -> zeroed)
#define ZERO_WORDS (OFF_AGG + N_NODES_ * 88)  // zero M + cs + cnt + agg (~17.8MB)
#define OFF_CUR    ZERO_WORDS                 // [N] int scan/cursor
#define OFF_PART   (OFF_CUR + N_NODES_)       // [64] int scan partials
#define OFF_PERM   (OFF_PART + 64)            // [E] int edge permutation
#define OFF_V      (OFF_PERM + E_EDGES)       // [88*128] fp32 M@W1
#define OFF_S      (OFF_V + 88 * 128)         // [128]
#define OFF_T      (OFF_S + 128)              // [128]
#define OFF_MPART  (OFF_T + 128)              // [625 * 5376] fp32 per-block M partials

// ---------------------------------------------------------------------------
// FUSED kernel: one pass over ea in SORTED (perm) order computes BOTH
//   (a) M = G^T G via MFMA (edge-order invariant), flushed as per-block
//       partials -> m_reduce_kernel (R1 lesson: never same-address atomics)
//   (b) agg[row] = segment sums of [x[col], ea] via per-tile segmented scan
//       (sorted rows => ~8 runs/tile; flush = spread atomicAdd, ~5M atomics
//       over 4.4M addresses)
// This halves ea HBM traffic (was read by both m_kernel and agg_kernel) and
// removes one launch + one latency-bound pass.
// Staging: 2 threads per edge row (336B = 21 aligned float4s; h=0 takes
// chunks 0..10 + x[col], h=1 takes chunks 11..20). Register double-buffer:
// tile t+1's perm preloaded at t-1, its ea/eidx/x loads issued during t's
// compute (breaks the perm->ea dependent chain across phases).
// LDS: bf16 transposed Gs_t[feat][edge] for MFMA fragments (as before) +
// fp32 edge-major EAf[slot][96] with XOR-swizzled 16B chunks (conflict-free
// b128 writes and per-feature column reads).
// Occupancy: LDS 75.8KB -> 2 blocks/CU. launch_bounds(256,2) => VGPR cap
// 256, NO forced spill (R3 lesson: (256,6) forced VGPR 40 and +430MB of
// scratch traffic).
// ---------------------------------------------------------------------------
__global__ __launch_bounds__(256, 2)
void fused_kernel(const float* __restrict__ x, const int* __restrict__ eidx,
                  const float* __restrict__ ea, const int* __restrict__ perm,
                  float* __restrict__ mpart, float* __restrict__ agg)
{
    __shared__ __align__(16) short Gs_t[96 * 136];
    __shared__ __align__(16) float EAf[128 * 96];
    __shared__ int rL[128];

    const int tid  = threadIdx.x;
    const int lane = tid & 63;
    const int wave = tid >> 6;         // 0..3
    const int m    = lane & 15;
    const int q    = lane >> 4;        // 0..3
    const int slot = tid & 127;        // edge slot within tile
    const int h    = tid >> 7;         // half of the edge row

    f32x4 acc[6];
#pragma unroll
    for (int i = 0; i < 6; ++i) acc[i] = (f32x4){0.f, 0.f, 0.f, 0.f};

    // zero pad rows 88..95 once (staging never writes them)
    {
        int* gz = (int*)&Gs_t[88 * 136];
        for (int i = tid; i < 8 * 136 / 2; i += 256) gz[i] = 0;
    }

    // ---- prologue: tile0 regs + tile1 perm ----
    int tile = blockIdx.x;
    int pe   = perm[tile * 128 + slot];
    int rowe = eidx[pe];
    int cole = eidx[E_EDGES + pe];
    f32x4 rf[12];
    {
        const float* er = ea + (size_t)pe * 84;
        if (h == 0) {
#pragma unroll
            for (int i = 0; i < 11; ++i) rf[i + 1] = *(const f32x4*)(er + i * 4);
            rf[0] = *(const f32x4*)(x + (size_t)cole * 4);
        } else {
#pragma unroll
            for (int i = 0; i < 10; ++i) rf[i] = *(const f32x4*)(er + 44 + i * 4);
        }
    }
    int pf = perm[(tile + M_GRID) * 128 + slot];

#pragma unroll 1
    for (int it = 0; it < M_TILES; ++it) {
        __syncthreads();               // previous tile's MFMA + scan done

        // ---- stage bf16 transposed Gs_t[feat][slot] ----
        if (h == 0) {
#pragma unroll
            for (int j = 0; j < 4; ++j) {
                __hip_bfloat16 b = __float2bfloat16(rf[0][j]);
                Gs_t[j * 136 + slot] = *(short*)&b;
            }
#pragma unroll
            for (int i = 0; i < 11; ++i) {
#pragma unroll
                for (int j = 0; j < 4; ++j) {
                    __hip_bfloat16 b = __float2bfloat16(rf[i + 1][j]);
                    Gs_t[(4 + i * 4 + j) * 136 + slot] = *(short*)&b;
                }
            }
            rL[slot] = rowe;
        } else {
#pragma unroll
            for (int i = 0; i < 10; ++i) {
#pragma unroll
                for (int j = 0; j < 4; ++j) {
                    __hip_bfloat16 b = __float2bfloat16(rf[i][j]);
                    Gs_t[(48 + i * 4 + j) * 136 + slot] = *(short*)&b;
                }
            }
        }
        // ---- stage fp32 edge-major EAf[slot][feat], XOR-swizzled chunks ----
        {
            const int k  = (slot & 7) << 2;        // dword XOR key (bits 2..4)
            float* base  = EAf + slot * 96;
            if (h == 0) {
                *(f32x4*)(base + (0 ^ k)) = rf[0];  // features 0..3 = x[col]
#pragma unroll
                for (int i = 0; i < 11; ++i)
                    *(f32x4*)(base + ((4 + 4 * i) ^ k)) = rf[i + 1];
            } else {
#pragma unroll
                for (int i = 0; i < 10; ++i)
                    *(f32x4*)(base + ((48 + 4 * i) ^ k)) = rf[i];
            }
        }

        // ---- prefetch next tile into regs (overlaps MFMA + scan) ----
        if (it + 1 < M_TILES) {
            pe   = pf;
            rowe = eidx[pe];
            cole = eidx[E_EDGES + pe];
            const float* er = ea + (size_t)pe * 84;
            if (h == 0) {
#pragma unroll
                for (int i = 0; i < 11; ++i) rf[i + 1] = *(const f32x4*)(er + i * 4);
                rf[0] = *(const f32x4*)(x + (size_t)cole * 4);
            } else {
#pragma unroll
                for (int i = 0; i < 10; ++i) rf[i] = *(const f32x4*)(er + 44 + i * 4);
            }
            if (it + 2 < M_TILES)
                pf = perm[(tile + (it + 2) * M_GRID) * 128 + slot];
        }
        __syncthreads();

        // ---- MFMA: M partial accumulation (unchanged) ----
#pragma unroll
        for (int kk = 0; kk < 4; ++kk) {
            const int kbase = kk * 32 + q * 8;
            s16x8 fr[6];
#pragma unroll
            for (int p = 0; p < 6; ++p)
                fr[p] = *reinterpret_cast<const s16x8*>(
                            &Gs_t[(p * 16 + m) * 136 + kbase]);
#define MM(i, a, b) acc[i] = __builtin_amdgcn_mfma_f32_16x16x32_bf16(fr[a], fr[b], acc[i], 0, 0, 0)
            if      (wave == 0) { MM(0,0,0); MM(1,0,4); MM(2,1,3); MM(3,2,3); MM(4,3,4); MM(5,5,5); }
            else if (wave == 1) { MM(0,0,1); MM(1,0,5); MM(2,1,4); MM(3,2,4); MM(4,3,5); }
            else if (wave == 2) { MM(0,0,2); MM(1,1,1); MM(2,1,5); MM(3,2,5); MM(4,4,4); }
            else                { MM(0,0,3); MM(1,1,2); MM(2,2,2); MM(3,3,3); MM(4,4,5); }
#undef MM
        }

        // ---- segmented per-feature scan: agg flushes (22 lanes/wave) ----
        if (lane < 22) {
            const int f = wave * 22 + lane;     // 0..87, each feature once
            float a  = 0.f;
            int  cur = rL[0];
#pragma unroll 8
            for (int s = 0; s < 128; ++s) {
                const int   row = rL[s];                       // broadcast
                const float v   = EAf[s * 96 + (f ^ ((s & 7) << 2))];
                if (row != cur) {                              // uniform branch
                    atomicAdd(&agg[(size_t)cur * 88 + f], a);
                    a = 0.f; cur = row;
                }
                a += v;
            }
            atomicAdd(&agg[(size_t)cur * 88 + f], a);
        }
    }

    // flush M partials: coalesced stores, reduced by m_reduce_kernel
    {
        float* pb = mpart + (size_t)blockIdx.x * 5376;
        const int nt = (wave == 0) ? 6 : 5;
#pragma unroll
        for (int i = 0; i < 6; ++i) {
            if (i < nt) {
                const int k = wave + i * 4;
                *(f32x4*)(pb + k * 256 + m * 16 + q * 4) = acc[i];
            }
        }
    }
}

// reduce per-block M partials into M. grid = 5376*M_SPLITS/256 blocks.
__global__ __launch_bounds__(256)
void m_reduce_kernel(const float* __restrict__ mpart, float* __restrict__ M)
{
    const int g     = blockIdx.x * 256 + threadIdx.x;
    const int pos   = g % 5376;
    const int split = g / 5376;
    const int b0    = split * (M_GRID / M_SPLITS);
    const int b1    = b0 + (M_GRID / M_SPLITS);

    float s = 0.f;
#pragma unroll 5
    for (int b = b0; b < b1; ++b) s += mpart[(size_t)b * 5376 + pos];

    const int k  = pos >> 8;
    const int wi = pos & 255;
    const int m  = wi >> 4;
    const int qr = wi & 15;
    const int tr = (k >= 20) ? 5 : (k >= 18) ? 4 : (k >= 15) ? 3
                 : (k >= 11) ? 2 : (k >= 6) ? 1 : 0;
    const int S  = (tr == 5) ? 20 : (tr == 4) ? 18 : (tr == 3) ? 15
                 : (tr == 2) ? 11 : (tr == 1) ? 6 : 0;
    const int tc = tr + (k - S);
    const int rr = tr * 16 + qr;
    const int c  = tc * 16 + m;
    if (rr < 88 && c < 88) {
        atomicAdd(&M[rr * 88 + c], s);
        if (tr != tc) atomicAdd(&M[c * 88 + rr], s);
    }
}

// ---- counting sort: histogram -> scan -> scatter ----
__global__ void hist_kernel(const int* __restrict__ eidx, int* __restrict__ cnt)
{
    int e = blockIdx.x * 256 + threadIdx.x;
    if (e < E_EDGES) atomicAdd(&cnt[eidx[e]], 1);
}

__global__ void scan1_kernel(const int* __restrict__ cnt, int* __restrict__ partial)
{
    __shared__ int l[1024];
    int i = blockIdx.x * 1024 + threadIdx.x;
    l[threadIdx.x] = (i < N_NODES_) ? cnt[i] : 0;
    __syncthreads();
    for (int s = 512; s > 0; s >>= 1) {
        if (threadIdx.x < s) l[threadIdx.x] += l[threadIdx.x + s];
        __syncthreads();
    }
    if (threadIdx.x == 0) partial[blockIdx.x] = l[0];
}

__global__ void scan2_kernel(int* __restrict__ partial)
{
    if (threadIdx.x == 0) {
        int acc = 0;
        for (int i = 0; i < N_SCAN_BLOCKS; ++i) {
            int t = partial[i]; partial[i] = acc; acc += t;
        }
    }
}

__global__ void scan3_kernel(const int* __restrict__ cnt, const int* __restrict__ partial,
                             int* __restrict__ cursor)
{
    __shared__ int l[1024];
    int i = blockIdx.x * 1024 + threadIdx.x;
    int v = (i < N_NODES_) ? cnt[i] : 0;
    l[threadIdx.x] = v;
    __syncthreads();
    for (int s = 1; s < 1024; s <<= 1) {
        int t = (threadIdx.x >= s) ? l[threadIdx.x - s] : 0;
        __syncthreads();
        l[threadIdx.x] += t;
        __syncthreads();
    }
    if (i < N_NODES_) cursor[i] = partial[blockIdx.x] + l[threadIdx.x] - v; // exclusive
}

__global__ void scatter_kernel(const int* __restrict__ eidx, int* __restrict__ cursor,
                               int* __restrict__ perm)
{
    int e = blockIdx.x * 256 + threadIdx.x;
    if (e < E_EDGES) {
        int pos = atomicAdd(&cursor[eidx[e]], 1);
        perm[pos] = e;
    }
}

// cs[f] = sum over nodes of agg[n][f]
__global__ void colsum_kernel(const float* __restrict__ agg, float* __restrict__ cs)
{
    const int f = threadIdx.x;
    if (f >= 88) return;
    float a = 0.f;
    for (int n = blockIdx.x; n < N_NODES_; n += gridDim.x) a += agg[n * 88 + f];
    atomicAdd(&cs[f], a);
}

// v = M @ W1   [88 x 128]
__global__ void mv_kernel(const float* __restrict__ M, const float* __restrict__ W1,
                          float* __restrict__ v)
{
    const int a = blockIdx.x;
    const int j = threadIdx.x;
    float acc = 0.f;
    for (int b = 0; b < 88; ++b) acc += M[a * 88 + b] * W1[b * 128 + j];
    v[a * 128 + j] = acc;
}

__global__ void stats_kernel(const float* __restrict__ cs, const float* __restrict__ v,
                             const float* __restrict__ W1, const float* __restrict__ b1,
                             const float* __restrict__ gamma, const float* __restrict__ beta,
                             float* __restrict__ s, float* __restrict__ t)
{
    const int j = threadIdx.x;
    const float invE = 1.0f / (float)E_EDGES;
    float mu = 0.f, eh2 = 0.f;
    for (int a = 0; a < 88; ++a) {
        float w = W1[a * 128 + j];
        mu  += cs[a] * w;
        eh2 += v[a * 128 + j] * w;
    }
    mu *= invE;
    eh2 *= invE;
    float var  = eh2 - mu * mu;
    float mean = mu + b1[j];
    float inv  = rsqrtf(var + EPS_);
    float sj   = gamma[j] * inv;
    s[j] = sj;
    t[j] = beta[j] - mean * sj;
}

__global__ __launch_bounds__(128)
void node_kernel(const float* __restrict__ x, const float* __restrict__ agg,
                 const int* __restrict__ cnt, const float* __restrict__ W1,
                 const float* __restrict__ b1, const float* __restrict__ W2,
                 const float* __restrict__ b2, const float* __restrict__ s,
                 const float* __restrict__ t, float* __restrict__ out)
{
    __shared__ float aggL[4 * 88];
    __shared__ float featL[4][128];
    __shared__ float cntL[4];
    __shared__ float xL[16];
    const int tid = threadIdx.x;
    const int nbase = blockIdx.x * 4;

    for (int i = tid; i < 352; i += 128) aggL[i] = agg[nbase * 88 + i];
    if (tid < 4)  cntL[tid] = (float)cnt[nbase + tid];
    if (tid < 16) xL[tid] = x[nbase * 4 + tid];
    __syncthreads();

    {
        const int j = tid;
        float a0 = 0.f, a1 = 0.f, a2 = 0.f, a3 = 0.f;
        for (int a = 0; a < 88; ++a) {
            float w = W1[a * 128 + j];
            a0 += aggL[a]       * w;
            a1 += aggL[88 + a]  * w;
            a2 += aggL[176 + a] * w;
            a3 += aggL[264 + a] * w;
        }
        const float sj = s[j], tj = t[j], bj = b1[j];
        float accs[4] = {a0, a1, a2, a3};
#pragma unroll
        for (int n = 0; n < 4; ++n) {
            float c = cntL[n];
            featL[n][j] = (c > 0.f) ? (sj * (accs[n] / c + bj) + tj) : 0.f;
        }
    }
    __syncthreads();

    {
        const int jc = tid & 63;
        const int nh = tid >> 6;
#pragma unroll
        for (int h = 0; h < 2; ++h) {
            const int n = nh * 2 + h;
            float acc = b2[jc];
#pragma unroll
            for (int k = 0; k < 4; ++k) acc += xL[n * 4 + k] * W2[k * 64 + jc];
            for (int k = 0; k < 128; ++k)
                acc += featL[n][k] * W2[(4 + k) * 64 + jc];
            out[(nbase + n) * 64 + jc] = fmaxf(acc, 0.f);
        }
    }
}

extern "C" void kernel_launch(void* const* d_in, const int* in_sizes, int n_in,
                              void* d_out, int out_size, void* d_ws, size_t ws_size,
                              hipStream_t stream)
{
    const float* x     = (const float*)d_in[0];
    const int*   eidx  = (const int*)d_in[1];
    const float* ea    = (const float*)d_in[2];
    const float* W1    = (const float*)d_in[3];
    const float* b1    = (const float*)d_in[4];
    const float* gamma = (const float*)d_in[5];
    const float* beta  = (const float*)d_in[6];
    const float* W2    = (const float*)d_in[7];
    const float* b2    = (const float*)d_in[8];

    float* ws    = (float*)d_ws;
    float* M     = ws + OFF_M;
    float* cs    = ws + OFF_CS;
    int*   cnt   = (int*)(ws + OFF_CNT);
    float* agg   = ws + OFF_AGG;
    int*   cur   = (int*)(ws + OFF_CUR);
    int*   part  = (int*)(ws + OFF_PART);
    int*   perm  = (int*)(ws + OFF_PERM);
    float* v     = ws + OFF_V;
    float* s     = ws + OFF_S;
    float* t     = ws + OFF_T;
    float* mpart = ws + OFF_MPART;
    float* out   = (float*)d_out;

    hipMemsetAsync(d_ws, 0, (size_t)ZERO_WORDS * sizeof(float), stream);

    hist_kernel<<<(E_EDGES + 255) / 256, 256, 0, stream>>>(eidx, cnt);
    scan1_kernel<<<N_SCAN_BLOCKS, 1024, 0, stream>>>(cnt, part);
    scan2_kernel<<<1, 64, 0, stream>>>(part);
    scan3_kernel<<<N_SCAN_BLOCKS, 1024, 0, stream>>>(cnt, part, cur);
    scatter_kernel<<<(E_EDGES + 255) / 256, 256, 0, stream>>>(eidx, cur, perm);

    fused_kernel<<<M_GRID, 256, 0, stream>>>(x, eidx, ea, perm, mpart, agg);
    m_reduce_kernel<<<(5376 * M_SPLITS) / 256, 256, 0, stream>>>(mpart, M);

    colsum_kernel<<<512, 96, 0, stream>>>(agg, cs);
    mv_kernel<<<88, 128, 0, stream>>>(M, W1, v);
    stats_kernel<<<1, 128, 0, stream>>>(cs, v, W1, b1, gamma, beta, s, t);
    node_kernel<<<12500, 128, 0, stream>>>(x, agg, cnt, W1, b1, W2, b2, s, t, out);
}

// Round 5
// 690.171 us; speedup vs baseline: 1.2136x; 1.1365x over previous
//
#include <hip/hip_runtime.h>
#include <hip/hip_bf16.h>

#define E_EDGES 800000
#define N_NODES_ 50000
#define EPS_ 1e-5f
#define N_SCAN_BLOCKS 49   // ceil(50000/1024)

#define M_GRID   1250      // blocks in fused kernel
#define M_TILES  5         // 6250 tiles / 1250 blocks, exact
#define M_SPLITS 25        // reduce: 1250 blocks / 25 = 50 blocks per split

typedef float f32x4 __attribute__((ext_vector_type(4)));
typedef short s16x8 __attribute__((ext_vector_type(8)));

// Raw workgroup barrier: LDS-only ordering (lgkmcnt), does NOT drain vmcnt.
// __syncthreads() emits s_waitcnt vmcnt(0) before s_barrier, which drained
// our prefetch gathers BEFORE the compute phase every tile (R4: 285us at
// 1.15 TB/s, 15% occupancy, all pipes idle). Global loads here only write
// registers, so cross-wave visibility needs only lgkmcnt(0); the compiler
// still inserts precise vmcnt(N) waits at each register use.
#define BAR_LGKM() do { \
    asm volatile("s_waitcnt lgkmcnt(0)" ::: "memory"); \
    __builtin_amdgcn_s_barrier(); \
} while (0)

// ---- workspace layout (4-byte word offsets) ----
#define OFF_M      0                          // [88*88] fp32 (reduced into)
#define OFF_CS     (88 * 88)                  // [88] fp32 col sums
#define OFF_CNT    (OFF_CS + 88)              // [N] int histogram (atomics)
#define OFF_AGG    (OFF_CNT + N_NODES_)       // [N*88] fp32 (atomic agg -> zeroed)
#define ZERO_WORDS (OFF_AGG + N_NODES_ * 88)  // zero M + cs + cnt + agg (~17.8MB)
#define OFF_CUR    ZERO_WORDS                 // [N] int scan/cursor
#define OFF_PART   (OFF_CUR + N_NODES_)       // [64] int scan partials
#define OFF_PERM   (OFF_PART + 64)            // [E] int edge permutation
#define OFF_V      (OFF_PERM + E_EDGES)       // [88*128] fp32 M@W1
#define OFF_S      (OFF_V + 88 * 128)         // [128]
#define OFF_T      (OFF_S + 128)              // [128]
#define OFF_MPART  (OFF_T + 128)              // [1250 * 5376] fp32 per-block M partials

// ---------------------------------------------------------------------------
// FUSED kernel: one pass over ea in SORTED (perm) order computes BOTH
//   (a) M = G^T G via MFMA (edge-order invariant), flushed as per-block
//       partials -> m_reduce_kernel
//   (b) agg[row] = segment sums of [x[col], ea] via per-tile segmented scan
// R5 changes vs R4 (which was latency-bound, not BW-bound):
//   - raw lgkm-only barriers (BAR_LGKM): prefetch gathers stay in flight
//     across barriers, hidden under MFMA+scan
//   - slot-split scan: wave w scans slots [32w,32w+32) for features
//     {lane, 64+lane} -> 4x shorter serial chain, 64 active lanes
//   - M_GRID 625->1250 (5 tiles/block)
// Numerics identical to R4 (fp32 EAf for agg; bf16 only for M as before).
// ---------------------------------------------------------------------------
__global__ __launch_bounds__(256, 2)
void fused_kernel(const float* __restrict__ x, const int* __restrict__ eidx,
                  const float* __restrict__ ea, const int* __restrict__ perm,
                  float* __restrict__ mpart, float* __restrict__ agg)
{
    __shared__ __align__(16) short Gs_t[96 * 136];
    __shared__ __align__(16) float EAf[128 * 96];
    __shared__ int rL[128];

    const int tid  = threadIdx.x;
    const int lane = tid & 63;
    const int wave = tid >> 6;         // 0..3
    const int m    = lane & 15;
    const int q    = lane >> 4;        // 0..3
    const int slot = tid & 127;        // edge slot within tile
    const int h    = tid >> 7;         // half of the edge row (wave-uniform)

    f32x4 acc[6];
#pragma unroll
    for (int i = 0; i < 6; ++i) acc[i] = (f32x4){0.f, 0.f, 0.f, 0.f};

    // zero pad rows 88..95 once (staging never writes them)
    {
        int* gz = (int*)&Gs_t[88 * 136];
        for (int i = tid; i < 8 * 136 / 2; i += 256) gz[i] = 0;
    }

    // ---- prologue: tile0 regs + tile1 perm ----
    const int tile = blockIdx.x;
    int pe   = perm[tile * 128 + slot];
    int rowe = eidx[pe];
    int cole = eidx[E_EDGES + pe];
    f32x4 rf[12];
    {
        const float* er = ea + (size_t)pe * 84;
        if (h == 0) {
#pragma unroll
            for (int i = 0; i < 11; ++i) rf[i + 1] = *(const f32x4*)(er + i * 4);
            rf[0] = *(const f32x4*)(x + (size_t)cole * 4);
        } else {
#pragma unroll
            for (int i = 0; i < 10; ++i) rf[i] = *(const f32x4*)(er + 44 + i * 4);
        }
    }
    int pf = perm[(tile + M_GRID) * 128 + slot];

#pragma unroll 1
    for (int it = 0; it < M_TILES; ++it) {
        BAR_LGKM();                    // previous tile's LDS reads retired

        // ---- stage bf16 transposed Gs_t[feat][slot] ----
        if (h == 0) {
#pragma unroll
            for (int j = 0; j < 4; ++j) {
                __hip_bfloat16 b = __float2bfloat16(rf[0][j]);
                Gs_t[j * 136 + slot] = *(short*)&b;
            }
#pragma unroll
            for (int i = 0; i < 11; ++i) {
#pragma unroll
                for (int j = 0; j < 4; ++j) {
                    __hip_bfloat16 b = __float2bfloat16(rf[i + 1][j]);
                    Gs_t[(4 + i * 4 + j) * 136 + slot] = *(short*)&b;
                }
            }
            rL[slot] = rowe;
        } else {
#pragma unroll
            for (int i = 0; i < 10; ++i) {
#pragma unroll
                for (int j = 0; j < 4; ++j) {
                    __hip_bfloat16 b = __float2bfloat16(rf[i][j]);
                    Gs_t[(48 + i * 4 + j) * 136 + slot] = *(short*)&b;
                }
            }
        }
        // ---- stage fp32 edge-major EAf[slot][feat], XOR-swizzled chunks ----
        {
            const int k  = (slot & 7) << 2;        // dword XOR key (bits 2..4)
            float* base  = EAf + slot * 96;
            if (h == 0) {
                *(f32x4*)(base + (0 ^ k)) = rf[0];  // features 0..3 = x[col]
#pragma unroll
                for (int i = 0; i < 11; ++i)
                    *(f32x4*)(base + ((4 + 4 * i) ^ k)) = rf[i + 1];
            } else {
#pragma unroll
                for (int i = 0; i < 10; ++i)
                    *(f32x4*)(base + ((48 + 4 * i) ^ k)) = rf[i];
            }
        }

        // ---- prefetch next tile into regs (overlaps MFMA + scan thanks to
        //      lgkm-only barriers; waited by compiler at next stage) ----
        if (it + 1 < M_TILES) {
            pe   = pf;
            rowe = eidx[pe];
            cole = eidx[E_EDGES + pe];
            const float* er = ea + (size_t)pe * 84;
            if (h == 0) {
#pragma unroll
                for (int i = 0; i < 11; ++i) rf[i + 1] = *(const f32x4*)(er + i * 4);
                rf[0] = *(const f32x4*)(x + (size_t)cole * 4);
            } else {
#pragma unroll
                for (int i = 0; i < 10; ++i) rf[i] = *(const f32x4*)(er + 44 + i * 4);
            }
            if (it + 2 < M_TILES)
                pf = perm[(tile + (it + 2) * M_GRID) * 128 + slot];
        }
        BAR_LGKM();                    // staging visible to all waves

        // ---- MFMA: M partial accumulation (unchanged) ----
#pragma unroll
        for (int kk = 0; kk < 4; ++kk) {
            const int kbase = kk * 32 + q * 8;
            s16x8 fr[6];
#pragma unroll
            for (int p = 0; p < 6; ++p)
                fr[p] = *reinterpret_cast<const s16x8*>(
                            &Gs_t[(p * 16 + m) * 136 + kbase]);
#define MM(i, a, b) acc[i] = __builtin_amdgcn_mfma_f32_16x16x32_bf16(fr[a], fr[b], acc[i], 0, 0, 0)
            if      (wave == 0) { MM(0,0,0); MM(1,0,4); MM(2,1,3); MM(3,2,3); MM(4,3,4); MM(5,5,5); }
            else if (wave == 1) { MM(0,0,1); MM(1,0,5); MM(2,1,4); MM(3,2,4); MM(4,3,5); }
            else if (wave == 2) { MM(0,0,2); MM(1,1,1); MM(2,1,5); MM(3,2,5); MM(4,4,4); }
            else                { MM(0,0,3); MM(1,1,2); MM(2,2,2); MM(3,3,3); MM(4,4,5); }
#undef MM
        }

        // ---- slot-split segmented scan: wave w owns slots [32w, 32w+32),
        //      lane owns feature f0=lane (and f1=64+lane for lane<24) ----
        {
            const int s0 = wave * 32;
            const int f0 = lane;
            const int f1 = 64 + lane;
            float a0 = 0.f, a1 = 0.f;
            int cur = rL[s0];
#pragma unroll 4
            for (int s = s0; s < s0 + 32; ++s) {
                const int row = rL[s];                         // broadcast
                const int kk2 = (s & 7) << 2;
                const float v0 = EAf[s * 96 + (f0 ^ kk2)];
                const float v1 = (lane < 24) ? EAf[s * 96 + (f1 ^ kk2)] : 0.f;
                if (row != cur) {                              // uniform branch
                    atomicAdd(&agg[(size_t)cur * 88 + f0], a0);
                    if (lane < 24) atomicAdd(&agg[(size_t)cur * 88 + f1], a1);
                    a0 = 0.f; a1 = 0.f; cur = row;
                }
                a0 += v0; a1 += v1;
            }
            atomicAdd(&agg[(size_t)cur * 88 + f0], a0);
            if (lane < 24) atomicAdd(&agg[(size_t)cur * 88 + f1], a1);
        }
    }

    // flush M partials: coalesced stores, reduced by m_reduce_kernel
    {
        float* pb = mpart + (size_t)blockIdx.x * 5376;
        const int nt = (wave == 0) ? 6 : 5;
#pragma unroll
        for (int i = 0; i < 6; ++i) {
            if (i < nt) {
                const int k = wave + i * 4;
                *(f32x4*)(pb + k * 256 + m * 16 + q * 4) = acc[i];
            }
        }
    }
}

// reduce per-block M partials into M. grid = 5376*M_SPLITS/256 blocks.
__global__ __launch_bounds__(256)
void m_reduce_kernel(const float* __restrict__ mpart, float* __restrict__ M)
{
    const int g     = blockIdx.x * 256 + threadIdx.x;
    const int pos   = g % 5376;
    const int split = g / 5376;
    const int b0    = split * (M_GRID / M_SPLITS);
    const int b1    = b0 + (M_GRID / M_SPLITS);

    float s = 0.f;
#pragma unroll 5
    for (int b = b0; b < b1; ++b) s += mpart[(size_t)b * 5376 + pos];

    const int k  = pos >> 8;
    const int wi = pos & 255;
    const int m  = wi >> 4;
    const int qr = wi & 15;
    const int tr = (k >= 20) ? 5 : (k >= 18) ? 4 : (k >= 15) ? 3
                 : (k >= 11) ? 2 : (k >= 6) ? 1 : 0;
    const int S  = (tr == 5) ? 20 : (tr == 4) ? 18 : (tr == 3) ? 15
                 : (tr == 2) ? 11 : (tr == 1) ? 6 : 0;
    const int tc = tr + (k - S);
    const int rr = tr * 16 + qr;
    const int c  = tc * 16 + m;
    if (rr < 88 && c < 88) {
        atomicAdd(&M[rr * 88 + c], s);
        if (tr != tc) atomicAdd(&M[c * 88 + rr], s);
    }
}

// ---- counting sort: histogram -> scan -> scatter ----
__global__ void hist_kernel(const int* __restrict__ eidx, int* __restrict__ cnt)
{
    int e = blockIdx.x * 256 + threadIdx.x;
    if (e < E_EDGES) atomicAdd(&cnt[eidx[e]], 1);
}

__global__ void scan1_kernel(const int* __restrict__ cnt, int* __restrict__ partial)
{
    __shared__ int l[1024];
    int i = blockIdx.x * 1024 + threadIdx.x;
    l[threadIdx.x] = (i < N_NODES_) ? cnt[i] : 0;
    __syncthreads();
    for (int s = 512; s > 0; s >>= 1) {
        if (threadIdx.x < s) l[threadIdx.x] += l[threadIdx.x + s];
        __syncthreads();
    }
    if (threadIdx.x == 0) partial[blockIdx.x] = l[0];
}

__global__ void scan2_kernel(int* __restrict__ partial)
{
    if (threadIdx.x == 0) {
        int acc = 0;
        for (int i = 0; i < N_SCAN_BLOCKS; ++i) {
            int t = partial[i]; partial[i] = acc; acc += t;
        }
    }
}

__global__ void scan3_kernel(const int* __restrict__ cnt, const int* __restrict__ partial,
                             int* __restrict__ cursor)
{
    __shared__ int l[1024];
    int i = blockIdx.x * 1024 + threadIdx.x;
    int v = (i < N_NODES_) ? cnt[i] : 0;
    l[threadIdx.x] = v;
    __syncthreads();
    for (int s = 1; s < 1024; s <<= 1) {
        int t = (threadIdx.x >= s) ? l[threadIdx.x - s] : 0;
        __syncthreads();
        l[threadIdx.x] += t;
        __syncthreads();
    }
    if (i < N_NODES_) cursor[i] = partial[blockIdx.x] + l[threadIdx.x] - v; // exclusive
}

__global__ void scatter_kernel(const int* __restrict__ eidx, int* __restrict__ cursor,
                               int* __restrict__ perm)
{
    int e = blockIdx.x * 256 + threadIdx.x;
    if (e < E_EDGES) {
        int pos = atomicAdd(&cursor[eidx[e]], 1);
        perm[pos] = e;
    }
}

// cs[f] = sum over nodes of agg[n][f]
__global__ void colsum_kernel(const float* __restrict__ agg, float* __restrict__ cs)
{
    const int f = threadIdx.x;
    if (f >= 88) return;
    float a = 0.f;
    for (int n = blockIdx.x; n < N_NODES_; n += gridDim.x) a += agg[n * 88 + f];
    atomicAdd(&cs[f], a);
}

// v = M @ W1   [88 x 128]
__global__ void mv_kernel(const float* __restrict__ M, const float* __restrict__ W1,
                          float* __restrict__ v)
{
    const int a = blockIdx.x;
    const int j = threadIdx.x;
    float acc = 0.f;
    for (int b = 0; b < 88; ++b) acc += M[a * 88 + b] * W1[b * 128 + j];
    v[a * 128 + j] = acc;
}

__global__ void stats_kernel(const float* __restrict__ cs, const float* __restrict__ v,
                             const float* __restrict__ W1, const float* __restrict__ b1,
                             const float* __restrict__ gamma, const float* __restrict__ beta,
                             float* __restrict__ s, float* __restrict__ t)
{
    const int j = threadIdx.x;
    const float invE = 1.0f / (float)E_EDGES;
    float mu = 0.f, eh2 = 0.f;
    for (int a = 0; a < 88; ++a) {
        float w = W1[a * 128 + j];
        mu  += cs[a] * w;
        eh2 += v[a * 128 + j] * w;
    }
    mu *= invE;
    eh2 *= invE;
    float var  = eh2 - mu * mu;
    float mean = mu + b1[j];
    float inv  = rsqrtf(var + EPS_);
    float sj   = gamma[j] * inv;
    s[j] = sj;
    t[j] = beta[j] - mean * sj;
}

__global__ __launch_bounds__(128)
void node_kernel(const float* __restrict__ x, const float* __restrict__ agg,
                 const int* __restrict__ cnt, const float* __restrict__ W1,
                 const float* __restrict__ b1, const float* __restrict__ W2,
                 const float* __restrict__ b2, const float* __restrict__ s,
                 const float* __restrict__ t, float* __restrict__ out)
{
    __shared__ float aggL[4 * 88];
    __shared__ float featL[4][128];
    __shared__ float cntL[4];
    __shared__ float xL[16];
    const int tid = threadIdx.x;
    const int nbase = blockIdx.x * 4;

    for (int i = tid; i < 352; i += 128) aggL[i] = agg[nbase * 88 + i];
    if (tid < 4)  cntL[tid] = (float)cnt[nbase + tid];
    if (tid < 16) xL[tid] = x[nbase * 4 + tid];
    __syncthreads();

    {
        const int j = tid;
        float a0 = 0.f, a1 = 0.f, a2 = 0.f, a3 = 0.f;
        for (int a = 0; a < 88; ++a) {
            float w = W1[a * 128 + j];
            a0 += aggL[a]       * w;
            a1 += aggL[88 + a]  * w;
            a2 += aggL[176 + a] * w;
            a3 += aggL[264 + a] * w;
        }
        const float sj = s[j], tj = t[j], bj = b1[j];
        float accs[4] = {a0, a1, a2, a3};
#pragma unroll
        for (int n = 0; n < 4; ++n) {
            float c = cntL[n];
            featL[n][j] = (c > 0.f) ? (sj * (accs[n] / c + bj) + tj) : 0.f;
        }
    }
    __syncthreads();

    {
        const int jc = tid & 63;
        const int nh = tid >> 6;
#pragma unroll
        for (int h = 0; h < 2; ++h) {
            const int n = nh * 2 + h;
            float acc = b2[jc];
#pragma unroll
            for (int k = 0; k < 4; ++k) acc += xL[n * 4 + k] * W2[k * 64 + jc];
            for (int k = 0; k < 128; ++k)
                acc += featL[n][k] * W2[(4 + k) * 64 + jc];
            out[(nbase + n) * 64 + jc] = fmaxf(acc, 0.f);
        }
    }
}

extern "C" void kernel_launch(void* const* d_in, const int* in_sizes, int n_in,
                              void* d_out, int out_size, void* d_ws, size_t ws_size,
                              hipStream_t stream)
{
    const float* x     = (const float*)d_in[0];
    const int*   eidx  = (const int*)d_in[1];
    const float* ea    = (const float*)d_in[2];
    const float* W1    = (const float*)d_in[3];
    const float* b1    = (const float*)d_in[4];
    const float* gamma = (const float*)d_in[5];
    const float* beta  = (const float*)d_in[6];
    const float* W2    = (const float*)d_in[7];
    const float* b2    = (const float*)d_in[8];

    float* ws    = (float*)d_ws;
    float* M     = ws + OFF_M;
    float* cs    = ws + OFF_CS;
    int*   cnt   = (int*)(ws + OFF_CNT);
    float* agg   = ws + OFF_AGG;
    int*   cur   = (int*)(ws + OFF_CUR);
    int*   part  = (int*)(ws + OFF_PART);
    int*   perm  = (int*)(ws + OFF_PERM);
    float* v     = ws + OFF_V;
    float* s     = ws + OFF_S;
    float* t     = ws + OFF_T;
    float* mpart = ws + OFF_MPART;
    float* out   = (float*)d_out;

    hipMemsetAsync(d_ws, 0, (size_t)ZERO_WORDS * sizeof(float), stream);

    hist_kernel<<<(E_EDGES + 255) / 256, 256, 0, stream>>>(eidx, cnt);
    scan1_kernel<<<N_SCAN_BLOCKS, 1024, 0, stream>>>(cnt, part);
    scan2_kernel<<<1, 64, 0, stream>>>(part);
    scan3_kernel<<<N_SCAN_BLOCKS, 1024, 0, stream>>>(cnt, part, cur);
    scatter_kernel<<<(E_EDGES + 255) / 256, 256, 0, stream>>>(eidx, cur, perm);

    fused_kernel<<<M_GRID, 256, 0, stream>>>(x, eidx, ea, perm, mpart, agg);
    m_reduce_kernel<<<(5376 * M_SPLITS) / 256, 256, 0, stream>>>(mpart, M);

    colsum_kernel<<<512, 96, 0, stream>>>(agg, cs);
    mv_kernel<<<88, 128, 0, stream>>>(M, W1, v);
    stats_kernel<<<1, 128, 0, stream>>>(cs, v, W1, b1, gamma, beta, s, t);
    node_kernel<<<12500, 128, 0, stream>>>(x, agg, cnt, W1, b1, W2, b2, s, t, out);
}